// Round 1
// baseline (694.469 us; speedup 1.0000x reference)
//
#include <hip/hip_runtime.h>
#include <stdint.h>

// Problem constants (from reference)
#define BTOT 7200      // BS*NQ
#define EPSV 1e-5f

using bf16x8 = __attribute__((ext_vector_type(8))) __bf16;
using f32x4  = __attribute__((ext_vector_type(4))) float;

// ---------------------------------------------------------------------------
// ws layout (bytes):
//   [0, 33554432)            W_pre split-bf16: 512 chunks x (hi 32KB | lo 32KB)
//   [33554432, 50331648)     W_aft split-bf16: 256 chunks x 64KB
//   [50331648, 52174848)     f1: 7200 x 64 f32
//   [52174848, 59547648)     f2: 7200 x 256 f32
// requires ws_size >= 59547648 (~57 MB)
// Chunk c holds W rows [c*64, c*64+64), layout hi[kb][j][e] at elem (kb*64+j)*8+e,
// kb = k>>3 (k in [0,256)), j = row%64, e = k&7.  Linear for global_load_lds,
// conflict-free for ds_read_b128 B-fragments (16 consecutive 16B slots / 16 lanes).
// ---------------------------------------------------------------------------

#define GLD16(gp, lp) __builtin_amdgcn_global_load_lds( \
    (const __attribute__((address_space(1))) uint32_t*)(gp), \
    (__attribute__((address_space(3))) uint32_t*)(lp), 16, 0, 0)

// copy one 64KB chunk (hi+lo) global -> LDS, linear; 512 threads
__device__ __forceinline__ void stage64k(char* ldsbase, const char* gsrc){
  const int w = (int)(threadIdx.x >> 6), lane = (int)(threadIdx.x & 63);
#pragma unroll
  for (int i = 0; i < 8; i++)
    GLD16(gsrc + i*8192 + w*1024 + lane*16, ldsbase + i*8192 + w*1024);
}

// ---------------------------------------------------------------------------
// Prep: split W_pre (32768x256) and W_aft (16384x256) fp32 -> bf16 hi/lo chunks
// grid: 6144 x 256  (512*2048 + 256*2048 threads, one 8-elem group each)
// ---------------------------------------------------------------------------
__global__ void prep_convert(const float* __restrict__ Wpre,
                             const float* __restrict__ Waft,
                             __bf16* __restrict__ dst)
{
  int g = (int)blockIdx.x * 256 + (int)threadIdx.x;
  const float* src;
  __bf16* d;
  if (g < 512*2048){ src = Wpre; d = dst; }
  else { g -= 512*2048; src = Waft; d = dst + (size_t)512*32768; }
  const int chunk = g >> 11, r = g & 2047;
  const int kb = r >> 6, j = r & 63;
  const float* sp = src + ((size_t)(chunk*64 + j))*256 + kb*8;
  float4 x0 = *(const float4*)sp;
  float4 x1 = *(const float4*)(sp + 4);
  float xs[8] = {x0.x,x0.y,x0.z,x0.w,x1.x,x1.y,x1.z,x1.w};
  bf16x8 hi, lo;
#pragma unroll
  for (int e = 0; e < 8; e++){
    __bf16 h = (__bf16)xs[e];
    hi[e] = h;
    lo[e] = (__bf16)(xs[e] - (float)h);
  }
  __bf16* base = d + (size_t)chunk*32768;
  *(bf16x8*)(base + r*8)        = hi;
  *(bf16x8*)(base + 16384 + r*8) = lo;
}

// ---------------------------------------------------------------------------
// Stage A: f1[b,d] = sum_k feats[b,k] * (q[b,:].W_pre[k*64+d,:] + b_pre[k*64+d])
// Fused GEMM(7200x32768x256) + weighted k-reduction. bf16x3 split precision.
// grid 228 = 57 b-tiles(128 rows) x 4 k-splits; 512 thr; 128KB LDS dbuf.
// js = bid&3 -> constant per XCD (bid%8) so co-resident WGs share W stream in L2.
// ---------------------------------------------------------------------------
__global__ __launch_bounds__(512, 2) void stageA(
    const float* __restrict__ query, const float* __restrict__ feats,
    const float* __restrict__ b_pre, const __bf16* __restrict__ W,
    float* __restrict__ f1)
{
  __shared__ char lds[2*65536];
  const int bid = (int)blockIdx.x;
  const int js = bid & 3, bt = bid >> 2;
  const int b0 = bt * 128;
  const int w = (int)threadIdx.x >> 6, lane = (int)threadIdx.x & 63;
  const int l15 = lane & 15, l4 = lane >> 4;
  const int rtb = (w & 3) * 2;      // row-tile base (2 tiles per wave)
  const int ch  = w >> 2;           // col half (32 cols)

  // Persistent A fragments: 2 row-tiles x 8 k-steps, hi+lo (128 VGPRs)
  bf16x8 ahi[2][8], alo[2][8];
#pragma unroll
  for (int rt = 0; rt < 2; rt++){
    const int row = b0 + (rtb + rt)*16 + l15;
    const bool v = row < BTOT;
    const float* qp = query + (size_t)row*256 + l4*8;
#pragma unroll
    for (int ks = 0; ks < 8; ks++){
      float xs[8];
      if (v){
        float4 q0 = *(const float4*)(qp + ks*32);
        float4 q1 = *(const float4*)(qp + ks*32 + 4);
        xs[0]=q0.x; xs[1]=q0.y; xs[2]=q0.z; xs[3]=q0.w;
        xs[4]=q1.x; xs[5]=q1.y; xs[6]=q1.z; xs[7]=q1.w;
      } else {
#pragma unroll
        for (int e = 0; e < 8; e++) xs[e] = 0.f;
      }
#pragma unroll
      for (int e = 0; e < 8; e++){
        __bf16 h = (__bf16)xs[e];
        ahi[rt][ks][e] = h;
        alo[rt][ks][e] = (__bf16)(xs[e] - (float)h);
      }
    }
  }

  f32x4 acc[2][2] = {};   // f1 accumulator: [rt][ct], rows x 32 d-cols (disjoint per wave)
  const char* wbase = (const char*)(W + (size_t)(js*128)*32768);

  stage64k(lds, wbase);
  __syncthreads();

  for (int cc2 = 0; cc2 < 64; cc2++){
#pragma unroll
    for (int u = 0; u < 2; u++){
      const int cc = cc2*2 + u;
      if (cc < 127) stage64k(lds + (u^1)*65536, wbase + (size_t)(cc+1)*65536);
      const __bf16* bufh = (const __bf16*)(lds + u*65536);
      const __bf16* bufl = bufh + 16384;

      f32x4 c[2][2] = {};
#pragma unroll
      for (int ks = 0; ks < 8; ks++){
        bf16x8 bh[2], bl[2];
#pragma unroll
        for (int ct = 0; ct < 2; ct++){
          const int off = ((ks*4 + l4)*64 + ch*32 + ct*16 + l15) * 8;
          bh[ct] = *(const bf16x8*)(bufh + off);
          bl[ct] = *(const bf16x8*)(bufl + off);
        }
#pragma unroll
        for (int rt = 0; rt < 2; rt++)
#pragma unroll
          for (int ct = 0; ct < 2; ct++)
            c[rt][ct] = __builtin_amdgcn_mfma_f32_16x16x32_bf16(ahi[rt][ks], bh[ct], c[rt][ct], 0,0,0);
#pragma unroll
        for (int rt = 0; rt < 2; rt++)
#pragma unroll
          for (int ct = 0; ct < 2; ct++)
            c[rt][ct] = __builtin_amdgcn_mfma_f32_16x16x32_bf16(ahi[rt][ks], bl[ct], c[rt][ct], 0,0,0);
#pragma unroll
        for (int rt = 0; rt < 2; rt++)
#pragma unroll
          for (int ct = 0; ct < 2; ct++)
            c[rt][ct] = __builtin_amdgcn_mfma_f32_16x16x32_bf16(alo[rt][ks], bh[ct], c[rt][ct], 0,0,0);
      }

      const int k = js*128 + cc;
#pragma unroll
      for (int ct = 0; ct < 2; ct++){
        const int dcol = ch*32 + ct*16 + l15;
        const float bias = b_pre[k*64 + dcol];
#pragma unroll
        for (int rt = 0; rt < 2; rt++){
#pragma unroll
          for (int i = 0; i < 4; i++){
            const int row = b0 + (rtb + rt)*16 + l4*4 + i;
            const float wv = (row < BTOT) ? feats[(size_t)row*512 + k] : 0.f;
            acc[rt][ct][i] += wv * (c[rt][ct][i] + bias);
          }
        }
      }
      __syncthreads();
    }
  }

#pragma unroll
  for (int rt = 0; rt < 2; rt++)
#pragma unroll
    for (int ct = 0; ct < 2; ct++)
#pragma unroll
      for (int i = 0; i < 4; i++){
        const int row = b0 + (rtb + rt)*16 + l4*4 + i;
        if (row < BTOT){
          const int dcol = ch*32 + ct*16 + l15;
          atomicAdd(&f1[(size_t)row*64 + dcol], acc[rt][ct][i]);
        }
      }
}

// ---------------------------------------------------------------------------
// Stage B: f2[b,e] = sum_d fln1[b,d] * (q[b,:].W_aft[d*256+e,:] + b_aft[d*256+e])
// grid 226 = 113 b-tiles(64 rows) x 2 d-splits; 512 thr; 128KB LDS dbuf.
// ---------------------------------------------------------------------------
__global__ __launch_bounds__(512, 2) void stageB(
    const float* __restrict__ query, const float* __restrict__ fln1,
    const float* __restrict__ b_aft, const __bf16* __restrict__ W,
    float* __restrict__ f2)
{
  __shared__ char lds[2*65536];
  const int bid = (int)blockIdx.x;
  const int js = bid & 1, bt = bid >> 1;
  const int b0 = bt * 64;
  const int w = (int)threadIdx.x >> 6, lane = (int)threadIdx.x & 63;
  const int l15 = lane & 15, l4 = lane >> 4;
  const int rt = w & 3;
  const int ch = w >> 2;

  bf16x8 ahi[8], alo[8];
  {
    const int row = b0 + rt*16 + l15;
    const bool v = row < BTOT;
    const float* qp = query + (size_t)row*256 + l4*8;
#pragma unroll
    for (int ks = 0; ks < 8; ks++){
      float xs[8];
      if (v){
        float4 q0 = *(const float4*)(qp + ks*32);
        float4 q1 = *(const float4*)(qp + ks*32 + 4);
        xs[0]=q0.x; xs[1]=q0.y; xs[2]=q0.z; xs[3]=q0.w;
        xs[4]=q1.x; xs[5]=q1.y; xs[6]=q1.z; xs[7]=q1.w;
      } else {
#pragma unroll
        for (int e = 0; e < 8; e++) xs[e] = 0.f;
      }
#pragma unroll
      for (int e = 0; e < 8; e++){
        __bf16 h = (__bf16)xs[e];
        ahi[ks][e] = h;
        alo[ks][e] = (__bf16)(xs[e] - (float)h);
      }
    }
  }

  f32x4 acc[4][2] = {};   // [e0-block][ct]
  const char* wbase = (const char*)(W + (size_t)(js*128)*32768);

  stage64k(lds, wbase);
  __syncthreads();

  for (int cc4 = 0; cc4 < 32; cc4++){
#pragma unroll
    for (int q = 0; q < 4; q++){          // q = e0-block, static (reg-array index)
      const int cc = cc4*4 + q;
      if (cc < 127) stage64k(lds + ((q&1)^1)*65536, wbase + (size_t)(cc+1)*65536);
      const __bf16* bufh = (const __bf16*)(lds + (q&1)*65536);
      const __bf16* bufl = bufh + 16384;

      f32x4 c0[2] = {}, c1[2] = {};
#pragma unroll
      for (int ks = 0; ks < 8; ks++){
        bf16x8 bh[2], bl[2];
#pragma unroll
        for (int ct = 0; ct < 2; ct++){
          const int off = ((ks*4 + l4)*64 + ch*32 + ct*16 + l15) * 8;
          bh[ct] = *(const bf16x8*)(bufh + off);
          bl[ct] = *(const bf16x8*)(bufl + off);
        }
#pragma unroll
        for (int ct = 0; ct < 2; ct++) c0[ct] = __builtin_amdgcn_mfma_f32_16x16x32_bf16(ahi[ks], bh[ct], c0[ct], 0,0,0);
#pragma unroll
        for (int ct = 0; ct < 2; ct++) c1[ct] = __builtin_amdgcn_mfma_f32_16x16x32_bf16(ahi[ks], bl[ct], c1[ct], 0,0,0);
#pragma unroll
        for (int ct = 0; ct < 2; ct++) c1[ct] = __builtin_amdgcn_mfma_f32_16x16x32_bf16(alo[ks], bh[ct], c1[ct], 0,0,0);
      }

      const int d = js*32 + cc4;
#pragma unroll
      for (int ct = 0; ct < 2; ct++){
        const int ecol = q*64 + ch*32 + ct*16 + l15;
        const float bias = b_aft[d*256 + ecol];
#pragma unroll
        for (int i = 0; i < 4; i++){
          const int row = b0 + rt*16 + l4*4 + i;
          const float wv = (row < BTOT) ? fln1[(size_t)row*64 + d] : 0.f;
          acc[q][ct][i] += wv * (c0[ct][i] + c1[ct][i] + bias);
        }
      }
      __syncthreads();
    }
  }

#pragma unroll
  for (int q = 0; q < 4; q++)
#pragma unroll
    for (int ct = 0; ct < 2; ct++)
#pragma unroll
      for (int i = 0; i < 4; i++){
        const int row = b0 + rt*16 + l4*4 + i;
        if (row < BTOT){
          const int e = q*64 + ch*32 + ct*16 + l15;
          atomicAdd(&f2[(size_t)row*256 + e], acc[q][ct][i]);
        }
      }
}

// ---------------------------------------------------------------------------
// In-place LayerNorm + ReLU, one wave per row. WID = 64 or 256.
// ---------------------------------------------------------------------------
template<int WID>
__global__ void ln_relu(float* __restrict__ x, const float* __restrict__ gamma,
                        const float* __restrict__ beta)
{
  const int wv = (int)threadIdx.x >> 6, lane = (int)threadIdx.x & 63;
  const int row = (int)blockIdx.x*4 + wv;
  if (row >= BTOT) return;
  float* xr = x + (size_t)row * WID;
  constexpr int PER = WID / 64;
  float v[PER];
  if constexpr (PER == 1){
    v[0] = xr[lane];
  } else {
    float4 t = *(const float4*)(xr + lane*4);
    v[0]=t.x; v[1]=t.y; v[2]=t.z; v[3]=t.w;
  }
  float s = 0.f, sq = 0.f;
#pragma unroll
  for (int p = 0; p < PER; p++){ s += v[p]; sq += v[p]*v[p]; }
#pragma unroll
  for (int off = 32; off > 0; off >>= 1){
    s  += __shfl_xor(s, off);
    sq += __shfl_xor(sq, off);
  }
  const float mu = s * (1.f/WID);
  const float var = sq * (1.f/WID) - mu*mu;
  const float rs = rsqrtf(var + EPSV);
#pragma unroll
  for (int p = 0; p < PER; p++){
    const int col = (PER == 1) ? lane : lane*4 + p;
    const float y = (v[p] - mu)*rs*gamma[col] + beta[col];
    v[p] = fmaxf(y, 0.f);
  }
  if constexpr (PER == 1){ xr[lane] = v[0]; }
  else {
    float4 t; t.x=v[0]; t.y=v[1]; t.z=v[2]; t.w=v[3];
    *(float4*)(xr + lane*4) = t;
  }
}

// ---------------------------------------------------------------------------
// Stage C: out = relu(LN3(fln2 @ W_out^T + b_out)). 16 rows / WG, fp32 vector.
// grid 450 x 256.  (0.9 GFLOP — small; W_out gathers L2-resident.)
// ---------------------------------------------------------------------------
__global__ __launch_bounds__(256) void stageC(
    const float* __restrict__ fln2, const float* __restrict__ Wout,
    const float* __restrict__ bout, const float* __restrict__ g3,
    const float* __restrict__ be3, float* __restrict__ out)
{
  __shared__ float xt[16][256];
  __shared__ float yt[16][256];
  const int t = (int)threadIdx.x;
  const int r0 = (int)blockIdx.x * 16;
#pragma unroll
  for (int i = 0; i < 16; i++) xt[i][t] = fln2[(size_t)(r0 + i)*256 + t];
  __syncthreads();
  const int lane = t & 63, wv = t >> 6;

  for (int ec = 0; ec < 4; ec++){
    const int e = ec*64 + lane;
    const float* wr = Wout + (size_t)e * 256;
    float a0=0.f, a1=0.f, a2=0.f, a3=0.f;
#pragma unroll 8
    for (int k4 = 0; k4 < 64; k4++){
      float4 wq = *(const float4*)(wr + k4*4);
      float4 x0 = *(const float4*)&xt[wv     ][k4*4];
      float4 x1 = *(const float4*)&xt[wv +  4][k4*4];
      float4 x2 = *(const float4*)&xt[wv +  8][k4*4];
      float4 x3 = *(const float4*)&xt[wv + 12][k4*4];
      a0 += x0.x*wq.x + x0.y*wq.y + x0.z*wq.z + x0.w*wq.w;
      a1 += x1.x*wq.x + x1.y*wq.y + x1.z*wq.z + x1.w*wq.w;
      a2 += x2.x*wq.x + x2.y*wq.y + x2.z*wq.z + x2.w*wq.w;
      a3 += x3.x*wq.x + x3.y*wq.y + x3.z*wq.z + x3.w*wq.w;
    }
    const float bb = bout[e];
    yt[wv     ][e] = a0 + bb;
    yt[wv +  4][e] = a1 + bb;
    yt[wv +  8][e] = a2 + bb;
    yt[wv + 12][e] = a3 + bb;
  }
  __syncthreads();

#pragma unroll
  for (int rr = 0; rr < 4; rr++){
    const int row = wv + rr*4;
    float4 v = *(const float4*)&yt[row][lane*4];
    float s  = v.x + v.y + v.z + v.w;
    float sq = v.x*v.x + v.y*v.y + v.z*v.z + v.w*v.w;
#pragma unroll
    for (int off = 32; off > 0; off >>= 1){
      s  += __shfl_xor(s, off);
      sq += __shfl_xor(sq, off);
    }
    const float mu = s * (1.f/256.f);
    const float var = sq * (1.f/256.f) - mu*mu;
    const float rs = rsqrtf(var + EPSV);
    const int c0 = lane*4;
    float4 o;
    o.x = fmaxf((v.x - mu)*rs*g3[c0  ] + be3[c0  ], 0.f);
    o.y = fmaxf((v.y - mu)*rs*g3[c0+1] + be3[c0+1], 0.f);
    o.z = fmaxf((v.z - mu)*rs*g3[c0+2] + be3[c0+2], 0.f);
    o.w = fmaxf((v.w - mu)*rs*g3[c0+3] + be3[c0+3], 0.f);
    *(float4*)(out + (size_t)(r0 + row)*256 + c0) = o;
  }
}

// ---------------------------------------------------------------------------
extern "C" void kernel_launch(void* const* d_in, const int* in_sizes, int n_in,
                              void* d_out, int out_size, void* d_ws, size_t ws_size,
                              hipStream_t stream)
{
  (void)in_sizes; (void)n_in; (void)out_size; (void)ws_size;
  const float* query = (const float*)d_in[0];
  const float* feats = (const float*)d_in[1];
  const float* Wpre  = (const float*)d_in[2];
  const float* bpre  = (const float*)d_in[3];
  const float* Waft  = (const float*)d_in[4];
  const float* baft  = (const float*)d_in[5];
  const float* Wout  = (const float*)d_in[6];
  const float* bout  = (const float*)d_in[7];
  const float* g1  = (const float*)d_in[8];
  const float* be1 = (const float*)d_in[9];
  const float* g2  = (const float*)d_in[10];
  const float* be2 = (const float*)d_in[11];
  const float* g3  = (const float*)d_in[12];
  const float* be3 = (const float*)d_in[13];
  float* outp = (float*)d_out;

  __bf16* wconv = (__bf16*)d_ws;                          // 50,331,648 B
  float* f1 = (float*)((char*)d_ws + 50331648);           // 1,843,200 B
  float* f2 = (float*)((char*)d_ws + 52174848);           // 7,372,800 B

  // f1/f2 are contiguous: zero both with one memset (ws re-poisoned each call)
  hipMemsetAsync(f1, 0, 1843200 + 7372800, stream);
  prep_convert<<<6144, 256, 0, stream>>>(Wpre, Waft, wconv);
  stageA<<<228, 512, 0, stream>>>(query, feats, bpre, wconv, f1);
  ln_relu<64><<<1800, 256, 0, stream>>>(f1, g1, be1);
  stageB<<<226, 512, 0, stream>>>(query, f1, baft, wconv + (size_t)512*32768, f2);
  ln_relu<256><<<1800, 256, 0, stream>>>(f2, g2, be2);
  stageC<<<450, 256, 0, stream>>>(f2, Wout, bout, g3, be3, outp);
}